// Round 8
// baseline (1245.837 us; speedup 1.0000x reference)
//
#include <hip/hip_runtime.h>
#include <stdint.h>

#define N_ELEM 16777216
#define NUM_SEG 1000000
#define SAMPLE_PAIRS 524288   // first 2^20 elements sampled in S1

typedef int   int4v   __attribute__((ext_vector_type(4)));
typedef float float2v __attribute__((ext_vector_type(2)));
typedef unsigned int uint4v __attribute__((ext_vector_type(4)));

// ws layout: [m0: 1M u32][m1: 1M u32][mb0: 1M u16][mb1: 1M u16] = 12 MB.
// m0/m1: exact f32-bit max tables (device-scope atomics, memory-side).
// mb0/mb1: bf16 tables. After convert1 they hold trunc16(sample max) and are
// READ-ONLY during S2 (so they stay L2-resident in every XCD with zero
// writeback traffic). After convert2 they hold RTNE(exact max) for the gather.

__global__ void gtsms_init_kernel(uint4v* __restrict__ ws) {
    int i = blockIdx.x * blockDim.x + threadIdx.x;
    if (i < NUM_SEG / 2) {                 // zero m0+m1: 2M u32 = 8 MB
        ws[i] = (uint4v){0u, 0u, 0u, 0u};
    }
}

// S1: unfiltered scatter-max of the sample prefix into the exact tables.
__global__ void gtsms_sample_kernel(const int* __restrict__ pp,
                                    const float* __restrict__ feat,
                                    unsigned int* __restrict__ m0,
                                    unsigned int* __restrict__ m1) {
    int i = blockIdx.x * blockDim.x + threadIdx.x;   // element-pair index
    if (i < SAMPLE_PAIRS) {
        int4v pr = __builtin_nontemporal_load(reinterpret_cast<const int4v*>(pp) + i);
        float2v fv = __builtin_nontemporal_load(reinterpret_cast<const float2v*>(feat) + i);
        unsigned int f0 = __float_as_uint(fv.x);
        unsigned int f1 = __float_as_uint(fv.y);
        atomicMax(&m0[pr.x], f0);
        atomicMax(&m1[pr.y], f0);
        atomicMax(&m0[pr.z], f1);
        atomicMax(&m1[pr.w], f1);
    }
}

// convert1: trunc16 (conservative lower bound) -> static filter mirror.
__global__ void gtsms_convert_trunc_kernel(const unsigned int* __restrict__ m0,
                                           const unsigned int* __restrict__ m1,
                                           unsigned short* __restrict__ mb0,
                                           unsigned short* __restrict__ mb1) {
    int i = blockIdx.x * blockDim.x + threadIdx.x;
    if (i < NUM_SEG) {
        mb0[i] = (unsigned short)(m0[i] >> 16);
        mb1[i] = (unsigned short)(m1[i] >> 16);
    }
}

// S2: all elements, filtered by the READ-ONLY mirror. mirror<<16 =
// trunc(sample max) <= value already committed in S1, so skipping
// f <= mirror can never drop the true max: exact tables end exact.
__global__ void gtsms_scatter_kernel(const int* __restrict__ pp,
                                     const float* __restrict__ feat,
                                     unsigned int* __restrict__ m0,
                                     unsigned int* __restrict__ m1,
                                     const unsigned short* __restrict__ mb0,
                                     const unsigned short* __restrict__ mb1) {
    int i = blockIdx.x * blockDim.x + threadIdx.x;   // element-pair index
    if (i < N_ELEM / 2) {
        int4v pr = __builtin_nontemporal_load(reinterpret_cast<const int4v*>(pp) + i);
        float2v fv = __builtin_nontemporal_load(reinterpret_cast<const float2v*>(feat) + i);
        unsigned int f0 = __float_as_uint(fv.x);
        unsigned int f1 = __float_as_uint(fv.y);
        unsigned int c00 = mb0[pr.x];
        unsigned int c01 = mb1[pr.y];
        unsigned int c10 = mb0[pr.z];
        unsigned int c11 = mb1[pr.w];
        if (f0 > (c00 << 16)) atomicMax(&m0[pr.x], f0);
        if (f0 > (c01 << 16)) atomicMax(&m1[pr.y], f0);
        if (f1 > (c10 << 16)) atomicMax(&m0[pr.z], f1);
        if (f1 > (c11 << 16)) atomicMax(&m1[pr.w], f1);
    }
}

// convert2: exact f32 tables -> RTNE bf16 tables for the gather.
__global__ void gtsms_convert_rtne_kernel(const unsigned int* __restrict__ m0,
                                          const unsigned int* __restrict__ m1,
                                          unsigned short* __restrict__ mb0,
                                          unsigned short* __restrict__ mb1) {
    int i = blockIdx.x * blockDim.x + threadIdx.x;
    if (i < NUM_SEG) {
        unsigned int u0 = m0[i];
        unsigned int u1 = m1[i];
        mb0[i] = (unsigned short)((u0 + 0x7FFFu + ((u0 >> 16) & 1u)) >> 16);
        mb1[i] = (unsigned short)((u1 + 0x7FFFu + ((u1 >> 16) & 1u)) >> 16);
    }
}

// Gather from the 4 MB read-only bf16 tables (L2-resident per XCD).
__global__ void gtsms_gather_kernel(const int* __restrict__ pp,
                                    const unsigned short* __restrict__ mb0,
                                    const unsigned short* __restrict__ mb1,
                                    float* __restrict__ out) {
    int i = blockIdx.x * blockDim.x + threadIdx.x;   // element-pair index
    if (i < N_ELEM / 2) {
        int4v pr = __builtin_nontemporal_load(reinterpret_cast<const int4v*>(pp) + i);
        float a0 = __uint_as_float(((unsigned int)mb0[pr.x]) << 16);
        float b0 = __uint_as_float(((unsigned int)mb1[pr.y]) << 16);
        float a1 = __uint_as_float(((unsigned int)mb0[pr.z]) << 16);
        float b1 = __uint_as_float(((unsigned int)mb1[pr.w]) << 16);
        float2v o;
        o.x = a0 * b0;
        o.y = a1 * b1;
        __builtin_nontemporal_store(o, reinterpret_cast<float2v*>(out) + i);
    }
}

extern "C" void kernel_launch(void* const* d_in, const int* in_sizes, int n_in,
                              void* d_out, int out_size, void* d_ws, size_t ws_size,
                              hipStream_t stream) {
    const int* pp = (const int*)d_in[0];          // (N,2) int32, row-major
    const float* feat = (const float*)d_in[1];    // (N,) float32
    float* out = (float*)d_out;                   // (N,) float32

    unsigned int* m0 = (unsigned int*)d_ws;                // 1M u32
    unsigned int* m1 = m0 + NUM_SEG;                       // 1M u32
    unsigned short* mb0 = (unsigned short*)(m1 + NUM_SEG); // 1M u16
    unsigned short* mb1 = mb0 + NUM_SEG;                   // 1M u16

    const int BLK = 256;
    dim3 initGrid((NUM_SEG / 2 + BLK - 1) / BLK);
    dim3 segGrid((NUM_SEG + BLK - 1) / BLK);
    dim3 sampleGrid((SAMPLE_PAIRS + BLK - 1) / BLK);
    dim3 pairGrid((N_ELEM / 2 + BLK - 1) / BLK);

    gtsms_init_kernel<<<initGrid, BLK, 0, stream>>>((uint4v*)d_ws);
    gtsms_sample_kernel<<<sampleGrid, BLK, 0, stream>>>(pp, feat, m0, m1);
    gtsms_convert_trunc_kernel<<<segGrid, BLK, 0, stream>>>(m0, m1, mb0, mb1);
    gtsms_scatter_kernel<<<pairGrid, BLK, 0, stream>>>(pp, feat, m0, m1, mb0, mb1);
    gtsms_convert_rtne_kernel<<<segGrid, BLK, 0, stream>>>(m0, m1, mb0, mb1);
    gtsms_gather_kernel<<<pairGrid, BLK, 0, stream>>>(pp, mb0, mb1, out);
}

// Round 9
// 835.461 us; speedup vs baseline: 1.4912x; 1.4912x over previous
//
#include <hip/hip_runtime.h>
#include <stdint.h>

#define N_ELEM 16777216
#define N_PAIR (N_ELEM / 2)
#define NUM_SEG 1000000

typedef int   int4v   __attribute__((ext_vector_type(4)));
typedef float float2v __attribute__((ext_vector_type(2)));
typedef float float4v __attribute__((ext_vector_type(4)));
typedef unsigned int uint4v __attribute__((ext_vector_type(4)));

// ws layout: [m0: 1M u32][m1: 1M u32][mb0: 1M u16][mb1: 1M u16] = 12 MB.
// m0/m1: exact f32-bit max tables (device-scope atomics, memory-side).
// mb0/mb1: bf16 mirror, READ-ONLY within each scatter chunk (L2-replicates,
// no writeback). Refreshed from the exact tables between chunks, so the
// filter is only one-chunk stale -> near-harmonic atomic count.
// Mirror value = trunc16(some committed exact value) <= true final max,
// so skipping f <= mirror<<16 never drops the true max. Exact stays exact.

__global__ void gtsms_init_kernel(uint4v* __restrict__ ws) {
    int i = blockIdx.x * blockDim.x + threadIdx.x;
    if (i < (3 * NUM_SEG) / 4) {          // zero all 12 MB (mirror = 0 too)
        ws[i] = (uint4v){0u, 0u, 0u, 0u};
    }
}

// One chunk of the filtered scatter: pairs [base, base + 2*nthreads).
// 4 elements (2 pair-records) per thread -> 8 independent mirror reads.
__global__ void gtsms_scatter_chunk(const int* __restrict__ pp,
                                    const float* __restrict__ feat,
                                    unsigned int* __restrict__ m0,
                                    unsigned int* __restrict__ m1,
                                    const unsigned short* __restrict__ mb0,
                                    const unsigned short* __restrict__ mb1,
                                    int base_pair, int n_threads) {
    int t = blockIdx.x * blockDim.x + threadIdx.x;
    if (t >= n_threads) return;
    int p = base_pair + 2 * t;
    int4v prA = __builtin_nontemporal_load(reinterpret_cast<const int4v*>(pp) + p);
    int4v prB = __builtin_nontemporal_load(reinterpret_cast<const int4v*>(pp) + p + 1);
    float2v fvA = __builtin_nontemporal_load(reinterpret_cast<const float2v*>(feat) + p);
    float2v fvB = __builtin_nontemporal_load(reinterpret_cast<const float2v*>(feat) + p + 1);
    unsigned int f0 = __float_as_uint(fvA.x);
    unsigned int f1 = __float_as_uint(fvA.y);
    unsigned int f2 = __float_as_uint(fvB.x);
    unsigned int f3 = __float_as_uint(fvB.y);
    // 8 independent 2B random loads in flight
    unsigned int c0 = mb0[prA.x];
    unsigned int c1 = mb1[prA.y];
    unsigned int c2 = mb0[prA.z];
    unsigned int c3 = mb1[prA.w];
    unsigned int c4 = mb0[prB.x];
    unsigned int c5 = mb1[prB.y];
    unsigned int c6 = mb0[prB.z];
    unsigned int c7 = mb1[prB.w];
    if (f0 > (c0 << 16)) atomicMax(&m0[prA.x], f0);
    if (f0 > (c1 << 16)) atomicMax(&m1[prA.y], f0);
    if (f1 > (c2 << 16)) atomicMax(&m0[prA.z], f1);
    if (f1 > (c3 << 16)) atomicMax(&m1[prA.w], f1);
    if (f2 > (c4 << 16)) atomicMax(&m0[prB.x], f2);
    if (f2 > (c5 << 16)) atomicMax(&m1[prB.y], f2);
    if (f3 > (c6 << 16)) atomicMax(&m0[prB.z], f3);
    if (f3 > (c7 << 16)) atomicMax(&m1[prB.w], f3);
}

// Refresh mirror = trunc16(exact) — conservative lower bound.
__global__ void gtsms_refresh_kernel(const unsigned int* __restrict__ m0,
                                     const unsigned int* __restrict__ m1,
                                     unsigned short* __restrict__ mb0,
                                     unsigned short* __restrict__ mb1) {
    int i = blockIdx.x * blockDim.x + threadIdx.x;
    if (i < NUM_SEG) {
        mb0[i] = (unsigned short)(m0[i] >> 16);
        mb1[i] = (unsigned short)(m1[i] >> 16);
    }
}

// Final: exact f32 tables -> RTNE bf16 tables for the gather.
__global__ void gtsms_convert_rtne_kernel(const unsigned int* __restrict__ m0,
                                          const unsigned int* __restrict__ m1,
                                          unsigned short* __restrict__ mb0,
                                          unsigned short* __restrict__ mb1) {
    int i = blockIdx.x * blockDim.x + threadIdx.x;
    if (i < NUM_SEG) {
        unsigned int u0 = m0[i];
        unsigned int u1 = m1[i];
        mb0[i] = (unsigned short)((u0 + 0x7FFFu + ((u0 >> 16) & 1u)) >> 16);
        mb1[i] = (unsigned short)((u1 + 0x7FFFu + ((u1 >> 16) & 1u)) >> 16);
    }
}

// Gather from the 4 MB read-only bf16 tables; 4 elements/thread.
__global__ void gtsms_gather_kernel(const int* __restrict__ pp,
                                    const unsigned short* __restrict__ mb0,
                                    const unsigned short* __restrict__ mb1,
                                    float* __restrict__ out) {
    int t = blockIdx.x * blockDim.x + threadIdx.x;
    if (t < N_PAIR / 2) {
        int p = 2 * t;
        int4v prA = __builtin_nontemporal_load(reinterpret_cast<const int4v*>(pp) + p);
        int4v prB = __builtin_nontemporal_load(reinterpret_cast<const int4v*>(pp) + p + 1);
        unsigned int a0 = mb0[prA.x];
        unsigned int b0 = mb1[prA.y];
        unsigned int a1 = mb0[prA.z];
        unsigned int b1 = mb1[prA.w];
        unsigned int a2 = mb0[prB.x];
        unsigned int b2 = mb1[prB.y];
        unsigned int a3 = mb0[prB.z];
        unsigned int b3 = mb1[prB.w];
        float4v o;
        o.x = __uint_as_float(a0 << 16) * __uint_as_float(b0 << 16);
        o.y = __uint_as_float(a1 << 16) * __uint_as_float(b1 << 16);
        o.z = __uint_as_float(a2 << 16) * __uint_as_float(b2 << 16);
        o.w = __uint_as_float(a3 << 16) * __uint_as_float(b3 << 16);
        __builtin_nontemporal_store(o, reinterpret_cast<float4v*>(out) + t);
    }
}

extern "C" void kernel_launch(void* const* d_in, const int* in_sizes, int n_in,
                              void* d_out, int out_size, void* d_ws, size_t ws_size,
                              hipStream_t stream) {
    const int* pp = (const int*)d_in[0];          // (N,2) int32, row-major
    const float* feat = (const float*)d_in[1];    // (N,) float32
    float* out = (float*)d_out;                   // (N,) float32

    unsigned int* m0 = (unsigned int*)d_ws;                // 1M u32
    unsigned int* m1 = m0 + NUM_SEG;                       // 1M u32
    unsigned short* mb0 = (unsigned short*)(m1 + NUM_SEG); // 1M u16
    unsigned short* mb1 = mb0 + NUM_SEG;                   // 1M u16

    const int BLK = 256;
    dim3 initGrid(((3 * NUM_SEG) / 4 + BLK - 1) / BLK);
    dim3 segGrid((NUM_SEG + BLK - 1) / BLK);
    dim3 gatherGrid((N_PAIR / 2 + BLK - 1) / BLK);

    gtsms_init_kernel<<<initGrid, BLK, 0, stream>>>((uint4v*)d_ws);

    // Geometric chunks (in pair units): 1/16, 1/16, 1/8, 1/4, 1/2 of N_PAIR.
    const int cb[6] = {0, N_PAIR / 16, N_PAIR / 8, N_PAIR / 4, N_PAIR / 2, N_PAIR};
    for (int c = 0; c < 5; ++c) {
        int base = cb[c];
        int n_threads = (cb[c + 1] - cb[c]) / 2;   // 2 pairs per thread
        dim3 g((n_threads + BLK - 1) / BLK);
        gtsms_scatter_chunk<<<g, BLK, 0, stream>>>(pp, feat, m0, m1, mb0, mb1,
                                                   base, n_threads);
        if (c < 4)
            gtsms_refresh_kernel<<<segGrid, BLK, 0, stream>>>(m0, m1, mb0, mb1);
    }

    gtsms_convert_rtne_kernel<<<segGrid, BLK, 0, stream>>>(m0, m1, mb0, mb1);
    gtsms_gather_kernel<<<gatherGrid, BLK, 0, stream>>>(pp, mb0, mb1, out);
}